// Round 2
// baseline (3098.417 us; speedup 1.0000x reference)
//
#include <hip/hip_runtime.h>
#include <hip/hip_bf16.h>

// Problem sizes (fixed by the reference)
#define NNODES 50000   // 3125 * 16 -> exact 16-row MFMA tiles
#define NEDGES 800000
#define NF 256         // input features
#define NH 128         // hidden
#define BN_EPS 1e-5f

typedef __attribute__((ext_vector_type(8))) __bf16 bf16x8;  // MFMA A/B frag (4 VGPRs)
typedef __attribute__((ext_vector_type(4))) float floatx4;  // MFMA C/D frag

__device__ __forceinline__ __hip_bfloat16 f2bf(float f) { return __float2bfloat16(f); }
__device__ __forceinline__ float bits2f(unsigned short b) {
    union { unsigned u; float f; } u; u.u = ((unsigned)b) << 16; return u.f;
}

// load 8 consecutive fp32, round to bf16x8 MFMA fragment
__device__ __forceinline__ bf16x8 cvt8(const float* __restrict__ p) {
    floatx4 a0 = *(const floatx4*)p;
    floatx4 a1 = *(const floatx4*)(p + 4);
    bf16x8 r;
    r[0] = (__bf16)a0[0]; r[1] = (__bf16)a0[1]; r[2] = (__bf16)a0[2]; r[3] = (__bf16)a0[3];
    r[4] = (__bf16)a1[0]; r[5] = (__bf16)a1[1]; r[6] = (__bf16)a1[2]; r[7] = (__bf16)a1[3];
    return r;
}

// ---------------------------------------------------------------------------
// h0 = relu(X[N,256] @ W[128,256]^T + b)  -> bf16 out [N,128]
// One wave per 16-row strip, all 8 column tiles (A-fragment loaded once).
// A-frag: lane holds X[m0+(lane&15)][k0+(lane>>4)*8 + j]
// B-frag: lane holds W[n0+(lane&15)][k0+(lane>>4)*8 + j]
// C/D: col = n0+(lane&15), row = m0+(lane>>4)*4 + r
// ---------------------------------------------------------------------------
__global__ __launch_bounds__(256) void gemm_in_kernel(
    const float* __restrict__ X, const float* __restrict__ W,
    const float* __restrict__ bias, __hip_bfloat16* __restrict__ out)
{
    const int wave = blockIdx.x * 4 + (threadIdx.x >> 6);
    if (wave >= NNODES / 16) return;              // 3125 m-tiles
    const int lane = threadIdx.x & 63;
    const int m0 = wave << 4;
    const int ar = lane & 15;
    const int q  = lane >> 4;

    floatx4 acc[8] = {};
    #pragma unroll
    for (int k0 = 0; k0 < NF; k0 += 32) {
        const bf16x8 a = cvt8(X + (size_t)(m0 + ar) * NF + k0 + q * 8);
        #pragma unroll
        for (int t = 0; t < 8; ++t) {
            const bf16x8 b = cvt8(W + (size_t)(t * 16 + ar) * NF + k0 + q * 8);
            acc[t] = __builtin_amdgcn_mfma_f32_16x16x32_bf16(a, b, acc[t], 0, 0, 0);
        }
    }
    #pragma unroll
    for (int t = 0; t < 8; ++t) {
        const int col = t * 16 + ar;
        const float bv = bias[col];
        #pragma unroll
        for (int r = 0; r < 4; ++r) {
            float v = fmaxf(acc[t][r] + bv, 0.f);
            out[(size_t)(m0 + q * 4 + r) * NH + col] = f2bf(v);
        }
    }
}

// ---------------------------------------------------------------------------
// agg[dst] += ew[e] * h[src]  (fp32 accumulation via HW atomics)
// 32 lanes per edge, 4 features per lane (8B bf16x4 load per lane).
// ---------------------------------------------------------------------------
__global__ __launch_bounds__(256) void scatter_kernel(
    const int* __restrict__ adj, const float* __restrict__ ew,
    const __hip_bfloat16* __restrict__ h, float* __restrict__ agg)
{
    const long long gt = (long long)blockIdx.x * blockDim.x + threadIdx.x;
    const int e = (int)(gt >> 5);
    const int l = (int)(gt & 31);
    if (e >= NEDGES) return;
    const int src = adj[e];           // adj[0][e]
    const int dst = adj[NEDGES + e];  // adj[1][e]
    const float w = ew[e];

    const uint2 raw = *(const uint2*)((const unsigned short*)h + (size_t)src * NH + l * 4);
    const float f0 = bits2f((unsigned short)(raw.x & 0xffffu));
    const float f1 = bits2f((unsigned short)(raw.x >> 16));
    const float f2 = bits2f((unsigned short)(raw.y & 0xffffu));
    const float f3 = bits2f((unsigned short)(raw.y >> 16));

    float* ap = agg + (size_t)dst * NH + l * 4;
    unsafeAtomicAdd(ap + 0, w * f0);
    unsafeAtomicAdd(ap + 1, w * f1);
    unsafeAtomicAdd(ap + 2, w * f2);
    unsafeAtomicAdd(ap + 3, w * f3);
}

// ---------------------------------------------------------------------------
// t = bf16(agg[N,128]) @ Wrel[128,128]^T + h[N,128] @ Wroot[128,128]^T + b
// fp32 output (pre-BN). One wave per 16-row strip, all 8 column tiles.
// ---------------------------------------------------------------------------
__global__ __launch_bounds__(256) void gemm_conv_kernel(
    const float* __restrict__ agg, const __hip_bfloat16* __restrict__ h,
    const float* __restrict__ Wrel, const float* __restrict__ Wroot,
    const float* __restrict__ bias, float* __restrict__ out)
{
    const int wave = blockIdx.x * 4 + (threadIdx.x >> 6);
    if (wave >= NNODES / 16) return;
    const int lane = threadIdx.x & 63;
    const int m0 = wave << 4;
    const int ar = lane & 15;
    const int q  = lane >> 4;

    floatx4 acc[8] = {};
    // chain 1: bf16(agg) @ Wrel^T
    #pragma unroll
    for (int k0 = 0; k0 < NH; k0 += 32) {
        const bf16x8 a = cvt8(agg + (size_t)(m0 + ar) * NH + k0 + q * 8);
        #pragma unroll
        for (int t = 0; t < 8; ++t) {
            const bf16x8 b = cvt8(Wrel + (size_t)(t * 16 + ar) * NH + k0 + q * 8);
            acc[t] = __builtin_amdgcn_mfma_f32_16x16x32_bf16(a, b, acc[t], 0, 0, 0);
        }
    }
    // chain 2: h @ Wroot^T
    #pragma unroll
    for (int k0 = 0; k0 < NH; k0 += 32) {
        const bf16x8 a = *(const bf16x8*)(h + (size_t)(m0 + ar) * NH + k0 + q * 8);
        #pragma unroll
        for (int t = 0; t < 8; ++t) {
            const bf16x8 b = cvt8(Wroot + (size_t)(t * 16 + ar) * NH + k0 + q * 8);
            acc[t] = __builtin_amdgcn_mfma_f32_16x16x32_bf16(a, b, acc[t], 0, 0, 0);
        }
    }
    #pragma unroll
    for (int t = 0; t < 8; ++t) {
        const int col = t * 16 + ar;
        const float bv = bias[col];
        #pragma unroll
        for (int r = 0; r < 4; ++r) {
            out[(size_t)(m0 + q * 4 + r) * NH + col] = acc[t][r] + bv;
        }
    }
}

// ---------------------------------------------------------------------------
// Column sums and sums-of-squares of t [N,128] fp32 -> stats[0..127]=sum, [128..255]=sumsq
// ---------------------------------------------------------------------------
__global__ __launch_bounds__(256) void col_stats_kernel(
    const float* __restrict__ t, float* __restrict__ stats)
{
    const int c = threadIdx.x & 127;
    const int rbase = blockIdx.x * 2 + (threadIdx.x >> 7);
    float s = 0.f, s2 = 0.f;
    for (int r = rbase; r < NNODES; r += gridDim.x * 2) {
        const float v = t[(size_t)r * NH + c];
        s += v; s2 += v * v;
    }
    __shared__ float ls[256], ls2[256];
    ls[threadIdx.x] = s; ls2[threadIdx.x] = s2;
    __syncthreads();
    if (threadIdx.x < 128) {
        s  = ls[threadIdx.x]  + ls[threadIdx.x + 128];
        s2 = ls2[threadIdx.x] + ls2[threadIdx.x + 128];
        unsafeAtomicAdd(&stats[c], s);
        unsafeAtomicAdd(&stats[128 + c], s2);
    }
}

// ---------------------------------------------------------------------------
// BN normalize: layer-1 variant writes relu(BN(t)) as bf16 (feeds next conv),
// layer-2 variant writes BN(t) as fp32 (final output, in-place on d_out).
// ---------------------------------------------------------------------------
__global__ __launch_bounds__(256) void bn_relu_bf16_kernel(
    const float* __restrict__ t, const float* __restrict__ stats,
    const float* __restrict__ gamma, const float* __restrict__ beta,
    __hip_bfloat16* __restrict__ out)
{
    const size_t i = (size_t)blockIdx.x * blockDim.x + threadIdx.x;  // exact grid
    const int c = (int)(i & (NH - 1));
    const float inv_n = 1.0f / (float)NNODES;
    const float mu = stats[c] * inv_n;
    const float var = stats[128 + c] * inv_n - mu * mu;
    const float rs = rsqrtf(var + BN_EPS);
    float v = (t[i] - mu) * rs * gamma[c] + beta[c];
    out[i] = f2bf(fmaxf(v, 0.f));
}

__global__ __launch_bounds__(256) void bn_f32_kernel(
    const float* __restrict__ t, const float* __restrict__ stats,
    const float* __restrict__ gamma, const float* __restrict__ beta,
    float* __restrict__ out)
{
    const size_t i = (size_t)blockIdx.x * blockDim.x + threadIdx.x;
    const int c = (int)(i & (NH - 1));
    const float inv_n = 1.0f / (float)NNODES;
    const float mu = stats[c] * inv_n;
    const float var = stats[128 + c] * inv_n - mu * mu;
    const float rs = rsqrtf(var + BN_EPS);
    out[i] = (t[i] - mu) * rs * gamma[c] + beta[c];
}

// ---------------------------------------------------------------------------

extern "C" void kernel_launch(void* const* d_in, const int* in_sizes, int n_in,
                              void* d_out, int out_size, void* d_ws, size_t ws_size,
                              hipStream_t stream)
{
    const float* x    = (const float*)d_in[0];
    const int*   adj  = (const int*)d_in[1];
    const float* ew   = (const float*)d_in[2];
    const float* W_in = (const float*)d_in[3];
    const float* b_in = (const float*)d_in[4];
    const float* W1r  = (const float*)d_in[5];
    const float* b1   = (const float*)d_in[6];
    const float* W1o  = (const float*)d_in[7];
    const float* W2r  = (const float*)d_in[8];
    const float* b2   = (const float*)d_in[9];
    const float* W2o  = (const float*)d_in[10];
    const float* gmm  = (const float*)d_in[11];
    const float* bta  = (const float*)d_in[12];
    float* out = (float*)d_out;          // fp32 output [N, NH]
    float* t   = (float*)d_out;          // pre-BN conv result lives in d_out

    char* ws = (char*)d_ws;
    __hip_bfloat16* h0 = (__hip_bfloat16*)ws; ws += (size_t)NNODES * NH * 2;  // 12.8 MB
    __hip_bfloat16* h1 = (__hip_bfloat16*)ws; ws += (size_t)NNODES * NH * 2;  // 12.8 MB
    float*          agg = (float*)ws;         ws += (size_t)NNODES * NH * 4;  // 25.6 MB
    float*          st  = (float*)ws;         ws += 256 * 4;

    const int gemm_blocks = (NNODES / 16 + 3) / 4;              // 782
    const int scat_blocks = (NEDGES * 32) / 256;                // 100000
    const int bn_blocks   = (NNODES * NH) / 256;                // 25000

    // ---- layer 1 ----
    hipMemsetAsync(agg, 0, (size_t)NNODES * NH * 4, stream);
    hipMemsetAsync(st, 0, 256 * 4, stream);
    gemm_in_kernel<<<gemm_blocks, 256, 0, stream>>>(x, W_in, b_in, h0);
    scatter_kernel<<<scat_blocks, 256, 0, stream>>>(adj, ew, h0, agg);
    gemm_conv_kernel<<<gemm_blocks, 256, 0, stream>>>(agg, h0, W1r, W1o, b1, t);
    col_stats_kernel<<<128, 256, 0, stream>>>(t, st);
    bn_relu_bf16_kernel<<<bn_blocks, 256, 0, stream>>>(t, st, gmm, bta, h1);

    // ---- layer 2 ----
    hipMemsetAsync(agg, 0, (size_t)NNODES * NH * 4, stream);
    hipMemsetAsync(st, 0, 256 * 4, stream);
    scatter_kernel<<<scat_blocks, 256, 0, stream>>>(adj, ew, h1, agg);
    gemm_conv_kernel<<<gemm_blocks, 256, 0, stream>>>(agg, h1, W2r, W2o, b2, t);
    col_stats_kernel<<<128, 256, 0, stream>>>(t, st);
    bn_f32_kernel<<<bn_blocks, 256, 0, stream>>>(t, st, gmm, bta, out);
}

// Round 3
// 785.657 us; speedup vs baseline: 3.9437x; 3.9437x over previous
//
#include <hip/hip_runtime.h>
#include <hip/hip_bf16.h>

// Problem sizes (fixed by the reference)
#define NNODES 50000   // 3125 * 16 -> exact 16-row MFMA tiles
#define NEDGES 800000
#define NF 256         // input features
#define NH 128         // hidden
#define BN_EPS 1e-5f

typedef __attribute__((ext_vector_type(8))) __bf16 bf16x8;  // MFMA A/B frag (4 VGPRs)
typedef __attribute__((ext_vector_type(4))) float floatx4;  // MFMA C/D frag

__device__ __forceinline__ __hip_bfloat16 f2bf(float f) { return __float2bfloat16(f); }
__device__ __forceinline__ float bits2f(unsigned short b) {
    union { unsigned u; float f; } u; u.u = ((unsigned)b) << 16; return u.f;
}

// load 8 consecutive fp32, round to bf16x8 MFMA fragment
__device__ __forceinline__ bf16x8 cvt8(const float* __restrict__ p) {
    floatx4 a0 = *(const floatx4*)p;
    floatx4 a1 = *(const floatx4*)(p + 4);
    bf16x8 r;
    r[0] = (__bf16)a0[0]; r[1] = (__bf16)a0[1]; r[2] = (__bf16)a0[2]; r[3] = (__bf16)a0[3];
    r[4] = (__bf16)a1[0]; r[5] = (__bf16)a1[1]; r[6] = (__bf16)a1[2]; r[7] = (__bf16)a1[3];
    return r;
}

// ---------------------------------------------------------------------------
// CSR build step 1: per-dst edge counts
// ---------------------------------------------------------------------------
__global__ __launch_bounds__(256) void hist_kernel(
    const int* __restrict__ adj, int* __restrict__ cnt)
{
    const int e = blockIdx.x * blockDim.x + threadIdx.x;
    if (e >= NEDGES) return;
    atomicAdd(&cnt[adj[NEDGES + e]], 1);
}

// ---------------------------------------------------------------------------
// CSR build step 2: exclusive prefix sum over 50000 counts (single block).
// rowptr[n] = start of node n; cursor[] = mutable copy for the sort.
// ---------------------------------------------------------------------------
__global__ __launch_bounds__(1024) void scan_kernel(
    const int* __restrict__ cnt, int* __restrict__ rowptr, int* __restrict__ cursor)
{
    __shared__ int part[1024];
    const int tid = threadIdx.x;
    const int CH = (NNODES + 1023) / 1024;  // 49
    const int base = tid * CH;
    int s = 0;
    for (int i = 0; i < CH; ++i) {
        const int idx = base + i;
        if (idx < NNODES) s += cnt[idx];
    }
    part[tid] = s;
    __syncthreads();
    for (int off = 1; off < 1024; off <<= 1) {
        const int v = (tid >= off) ? part[tid - off] : 0;
        __syncthreads();
        part[tid] += v;
        __syncthreads();
    }
    int run = (tid == 0) ? 0 : part[tid - 1];
    for (int i = 0; i < CH; ++i) {
        const int idx = base + i;
        if (idx < NNODES) {
            rowptr[idx] = run;
            cursor[idx] = run;
            run += cnt[idx];
        }
    }
    if (tid == 0) rowptr[NNODES] = NEDGES;  // total must equal E
}

// ---------------------------------------------------------------------------
// CSR build step 3: counting-sort edges by dst into (src, weight) pairs
// ---------------------------------------------------------------------------
__global__ __launch_bounds__(256) void sortbuild_kernel(
    const int* __restrict__ adj, const float* __restrict__ ew,
    int* __restrict__ cursor, uint2* __restrict__ sorted)
{
    const int e = blockIdx.x * blockDim.x + threadIdx.x;
    if (e >= NEDGES) return;
    const int dst = adj[NEDGES + e];
    const int pos = atomicAdd(&cursor[dst], 1);
    sorted[pos] = make_uint2((unsigned)adj[e], __float_as_uint(ew[e]));
}

// ---------------------------------------------------------------------------
// h0 = relu(X[N,256] @ W[128,256]^T + b)  -> bf16 out [N,128]
// One wave per 16-row strip, all 8 column tiles (A-fragment loaded once).
// C/D: col = n0+(lane&15), row = m0+(lane>>4)*4 + r
// ---------------------------------------------------------------------------
__global__ __launch_bounds__(256) void gemm_in_kernel(
    const float* __restrict__ X, const float* __restrict__ W,
    const float* __restrict__ bias, __hip_bfloat16* __restrict__ out)
{
    const int wave = blockIdx.x * 4 + (threadIdx.x >> 6);
    if (wave >= NNODES / 16) return;              // 3125 m-tiles
    const int lane = threadIdx.x & 63;
    const int m0 = wave << 4;
    const int ar = lane & 15;
    const int q  = lane >> 4;

    floatx4 acc[8] = {};
    #pragma unroll
    for (int k0 = 0; k0 < NF; k0 += 32) {
        const bf16x8 a = cvt8(X + (size_t)(m0 + ar) * NF + k0 + q * 8);
        #pragma unroll
        for (int t = 0; t < 8; ++t) {
            const bf16x8 b = cvt8(W + (size_t)(t * 16 + ar) * NF + k0 + q * 8);
            acc[t] = __builtin_amdgcn_mfma_f32_16x16x32_bf16(a, b, acc[t], 0, 0, 0);
        }
    }
    #pragma unroll
    for (int t = 0; t < 8; ++t) {
        const int col = t * 16 + ar;
        const float bv = bias[col];
        #pragma unroll
        for (int r = 0; r < 4; ++r) {
            float v = fmaxf(acc[t][r] + bv, 0.f);
            out[(size_t)(m0 + q * 4 + r) * NH + col] = f2bf(v);
        }
    }
}

// ---------------------------------------------------------------------------
// Gather-reduce: agg[n] = sum_{e in CSR[n]} w_e * h[src_e]   (bf16 out)
// One wave per node, 2 feats per lane, fp32 register accumulation.
// ---------------------------------------------------------------------------
__global__ __launch_bounds__(256) void gather_kernel(
    const uint2* __restrict__ sorted, const int* __restrict__ rowptr,
    const __hip_bfloat16* __restrict__ h, __hip_bfloat16* __restrict__ agg)
{
    const int node = blockIdx.x * 4 + (threadIdx.x >> 6);
    if (node >= NNODES) return;
    const int lane = threadIdx.x & 63;
    const int beg = rowptr[node];
    const int end = rowptr[node + 1];

    float a0 = 0.f, a1 = 0.f;
    const unsigned short* hb = (const unsigned short*)h;
    for (int j = beg; j < end; ++j) {
        const uint2 ev = sorted[j];                       // broadcast 8B
        const float w = __uint_as_float(ev.y);
        const unsigned raw = *(const unsigned*)(hb + (size_t)ev.x * NH + lane * 2);
        a0 += w * bits2f((unsigned short)(raw & 0xffffu));
        a1 += w * bits2f((unsigned short)(raw >> 16));
    }
    unsigned o = ((unsigned)__bfloat16_as_ushort(f2bf(a1)) << 16) |
                 (unsigned)__bfloat16_as_ushort(f2bf(a0));
    *(unsigned*)((unsigned short*)agg + (size_t)node * NH + lane * 2) = o;
}

// ---------------------------------------------------------------------------
// t = agg[N,128] @ Wrel[128,128]^T + h[N,128] @ Wroot[128,128]^T + b
// agg and h both bf16; fp32 output (pre-BN).
// ---------------------------------------------------------------------------
__global__ __launch_bounds__(256) void gemm_conv_kernel(
    const __hip_bfloat16* __restrict__ agg, const __hip_bfloat16* __restrict__ h,
    const float* __restrict__ Wrel, const float* __restrict__ Wroot,
    const float* __restrict__ bias, float* __restrict__ out)
{
    const int wave = blockIdx.x * 4 + (threadIdx.x >> 6);
    if (wave >= NNODES / 16) return;
    const int lane = threadIdx.x & 63;
    const int m0 = wave << 4;
    const int ar = lane & 15;
    const int q  = lane >> 4;

    floatx4 acc[8] = {};
    // chain 1: agg @ Wrel^T
    #pragma unroll
    for (int k0 = 0; k0 < NH; k0 += 32) {
        const bf16x8 a = *(const bf16x8*)(agg + (size_t)(m0 + ar) * NH + k0 + q * 8);
        #pragma unroll
        for (int t = 0; t < 8; ++t) {
            const bf16x8 b = cvt8(Wrel + (size_t)(t * 16 + ar) * NH + k0 + q * 8);
            acc[t] = __builtin_amdgcn_mfma_f32_16x16x32_bf16(a, b, acc[t], 0, 0, 0);
        }
    }
    // chain 2: h @ Wroot^T
    #pragma unroll
    for (int k0 = 0; k0 < NH; k0 += 32) {
        const bf16x8 a = *(const bf16x8*)(h + (size_t)(m0 + ar) * NH + k0 + q * 8);
        #pragma unroll
        for (int t = 0; t < 8; ++t) {
            const bf16x8 b = cvt8(Wroot + (size_t)(t * 16 + ar) * NH + k0 + q * 8);
            acc[t] = __builtin_amdgcn_mfma_f32_16x16x32_bf16(a, b, acc[t], 0, 0, 0);
        }
    }
    #pragma unroll
    for (int t = 0; t < 8; ++t) {
        const int col = t * 16 + ar;
        const float bv = bias[col];
        #pragma unroll
        for (int r = 0; r < 4; ++r) {
            out[(size_t)(m0 + q * 4 + r) * NH + col] = acc[t][r] + bv;
        }
    }
}

// ---------------------------------------------------------------------------
// Column sums and sums-of-squares of t [N,128] fp32
// ---------------------------------------------------------------------------
__global__ __launch_bounds__(256) void col_stats_kernel(
    const float* __restrict__ t, float* __restrict__ stats)
{
    const int c = threadIdx.x & 127;
    const int rbase = blockIdx.x * 2 + (threadIdx.x >> 7);
    float s = 0.f, s2 = 0.f;
    for (int r = rbase; r < NNODES; r += gridDim.x * 2) {
        const float v = t[(size_t)r * NH + c];
        s += v; s2 += v * v;
    }
    __shared__ float ls[256], ls2[256];
    ls[threadIdx.x] = s; ls2[threadIdx.x] = s2;
    __syncthreads();
    if (threadIdx.x < 128) {
        s  = ls[threadIdx.x]  + ls[threadIdx.x + 128];
        s2 = ls2[threadIdx.x] + ls2[threadIdx.x + 128];
        unsafeAtomicAdd(&stats[c], s);
        unsafeAtomicAdd(&stats[128 + c], s2);
    }
}

// ---------------------------------------------------------------------------
// BN normalize variants
// ---------------------------------------------------------------------------
__global__ __launch_bounds__(256) void bn_relu_bf16_kernel(
    const float* __restrict__ t, const float* __restrict__ stats,
    const float* __restrict__ gamma, const float* __restrict__ beta,
    __hip_bfloat16* __restrict__ out)
{
    const size_t i = (size_t)blockIdx.x * blockDim.x + threadIdx.x;  // exact grid
    const int c = (int)(i & (NH - 1));
    const float inv_n = 1.0f / (float)NNODES;
    const float mu = stats[c] * inv_n;
    const float var = stats[128 + c] * inv_n - mu * mu;
    const float rs = rsqrtf(var + BN_EPS);
    float v = (t[i] - mu) * rs * gamma[c] + beta[c];
    out[i] = f2bf(fmaxf(v, 0.f));
}

__global__ __launch_bounds__(256) void bn_f32_kernel(
    const float* __restrict__ t, const float* __restrict__ stats,
    const float* __restrict__ gamma, const float* __restrict__ beta,
    float* __restrict__ out)
{
    const size_t i = (size_t)blockIdx.x * blockDim.x + threadIdx.x;
    const int c = (int)(i & (NH - 1));
    const float inv_n = 1.0f / (float)NNODES;
    const float mu = stats[c] * inv_n;
    const float var = stats[128 + c] * inv_n - mu * mu;
    const float rs = rsqrtf(var + BN_EPS);
    out[i] = (t[i] - mu) * rs * gamma[c] + beta[c];
}

// ---------------------------------------------------------------------------

extern "C" void kernel_launch(void* const* d_in, const int* in_sizes, int n_in,
                              void* d_out, int out_size, void* d_ws, size_t ws_size,
                              hipStream_t stream)
{
    const float* x    = (const float*)d_in[0];
    const int*   adj  = (const int*)d_in[1];
    const float* ew   = (const float*)d_in[2];
    const float* W_in = (const float*)d_in[3];
    const float* b_in = (const float*)d_in[4];
    const float* W1r  = (const float*)d_in[5];
    const float* b1   = (const float*)d_in[6];
    const float* W1o  = (const float*)d_in[7];
    const float* W2r  = (const float*)d_in[8];
    const float* b2   = (const float*)d_in[9];
    const float* W2o  = (const float*)d_in[10];
    const float* gmm  = (const float*)d_in[11];
    const float* bta  = (const float*)d_in[12];
    float* out = (float*)d_out;          // fp32 output [N, NH]
    float* t   = (float*)d_out;          // pre-BN conv result lives in d_out

    char* ws = (char*)d_ws;
    __hip_bfloat16* h0  = (__hip_bfloat16*)ws; ws += (size_t)NNODES * NH * 2;  // 12.8 MB
    __hip_bfloat16* h1  = (__hip_bfloat16*)ws; ws += (size_t)NNODES * NH * 2;  // 12.8 MB
    __hip_bfloat16* agg = (__hip_bfloat16*)ws; ws += (size_t)NNODES * NH * 2;  // 12.8 MB
    uint2*          sorted = (uint2*)ws;       ws += (size_t)NEDGES * 8;       // 6.4 MB
    int*            rowptr = (int*)ws;         ws += (NNODES + 16) * 4;
    int*            cnt    = (int*)ws;         ws += NNODES * 4;
    int*            cursor = (int*)ws;         ws += NNODES * 4;
    float*          st     = (float*)ws;       ws += 256 * 4;

    const int gemm_blocks = (NNODES / 16 + 3) / 4;              // 782
    const int edge_blocks = (NEDGES + 255) / 256;               // 3125
    const int node_blocks = (NNODES + 3) / 4;                   // 12500
    const int bn_blocks   = (NNODES * NH) / 256;                // 25000

    // ---- CSR build (adjacency is shared by both layers) ----
    hipMemsetAsync(cnt, 0, NNODES * 4, stream);
    hist_kernel<<<edge_blocks, 256, 0, stream>>>(adj, cnt);
    scan_kernel<<<1, 1024, 0, stream>>>(cnt, rowptr, cursor);
    sortbuild_kernel<<<edge_blocks, 256, 0, stream>>>(adj, ew, cursor, sorted);

    // ---- layer 1 ----
    hipMemsetAsync(st, 0, 256 * 4, stream);
    gemm_in_kernel<<<gemm_blocks, 256, 0, stream>>>(x, W_in, b_in, h0);
    gather_kernel<<<node_blocks, 256, 0, stream>>>(sorted, rowptr, h0, agg);
    gemm_conv_kernel<<<gemm_blocks, 256, 0, stream>>>(agg, h0, W1r, W1o, b1, t);
    col_stats_kernel<<<128, 256, 0, stream>>>(t, st);
    bn_relu_bf16_kernel<<<bn_blocks, 256, 0, stream>>>(t, st, gmm, bta, h1);

    // ---- layer 2 ----
    hipMemsetAsync(st, 0, 256 * 4, stream);
    gather_kernel<<<node_blocks, 256, 0, stream>>>(sorted, rowptr, h1, agg);
    gemm_conv_kernel<<<gemm_blocks, 256, 0, stream>>>(agg, h1, W2r, W2o, b2, t);
    col_stats_kernel<<<128, 256, 0, stream>>>(t, st);
    bn_f32_kernel<<<bn_blocks, 256, 0, stream>>>(t, st, gmm, bta, out);
}

// Round 4
// 600.040 us; speedup vs baseline: 5.1637x; 1.3093x over previous
//
#include <hip/hip_runtime.h>
#include <hip/hip_bf16.h>

// Problem sizes (fixed by the reference)
#define NNODES 50000   // 3125 * 16 -> exact 16-row MFMA tiles
#define NEDGES 800000
#define NF 256         // input features
#define NH 128         // hidden
#define BN_EPS 1e-5f
#define SCAN_BLOCKS ((NNODES + 255) / 256)   // 196

typedef __attribute__((ext_vector_type(8))) __bf16 bf16x8;  // MFMA A/B frag (4 VGPRs)
typedef __attribute__((ext_vector_type(4))) float floatx4;  // MFMA C/D frag

__device__ __forceinline__ __hip_bfloat16 f2bf(float f) { return __float2bfloat16(f); }
__device__ __forceinline__ float bits2f(unsigned short b) {
    union { unsigned u; float f; } u; u.u = ((unsigned)b) << 16; return u.f;
}

// load 8 consecutive fp32, round to bf16x8 MFMA fragment
__device__ __forceinline__ bf16x8 cvt8(const float* __restrict__ p) {
    floatx4 a0 = *(const floatx4*)p;
    floatx4 a1 = *(const floatx4*)(p + 4);
    bf16x8 r;
    r[0] = (__bf16)a0[0]; r[1] = (__bf16)a0[1]; r[2] = (__bf16)a0[2]; r[3] = (__bf16)a0[3];
    r[4] = (__bf16)a1[0]; r[5] = (__bf16)a1[1]; r[6] = (__bf16)a1[2]; r[7] = (__bf16)a1[3];
    return r;
}

// ---------------------------------------------------------------------------
// CSR build step 1: per-dst edge counts
// ---------------------------------------------------------------------------
__global__ __launch_bounds__(256) void hist_kernel(
    const int* __restrict__ adj, int* __restrict__ cnt)
{
    const int e = blockIdx.x * blockDim.x + threadIdx.x;
    if (e >= NEDGES) return;
    atomicAdd(&cnt[adj[NEDGES + e]], 1);
}

// ---------------------------------------------------------------------------
// CSR build step 2: three-phase exclusive scan (coalesced, multi-block)
// ---------------------------------------------------------------------------
__global__ __launch_bounds__(256) void scan_a_kernel(
    const int* __restrict__ cnt, int* __restrict__ blocksum)
{
    const int idx = blockIdx.x * 256 + threadIdx.x;
    int v = (idx < NNODES) ? cnt[idx] : 0;
    __shared__ int red[256];
    red[threadIdx.x] = v;
    __syncthreads();
    for (int off = 128; off > 0; off >>= 1) {
        if (threadIdx.x < off) red[threadIdx.x] += red[threadIdx.x + off];
        __syncthreads();
    }
    if (threadIdx.x == 0) blocksum[blockIdx.x] = red[0];
}

__global__ __launch_bounds__(256) void scan_b_kernel(int* __restrict__ blocksum)
{
    __shared__ int s[256];
    const int tid = threadIdx.x;
    const int v = (tid < SCAN_BLOCKS) ? blocksum[tid] : 0;
    s[tid] = v;
    __syncthreads();
    for (int off = 1; off < 256; off <<= 1) {
        const int t = (tid >= off) ? s[tid - off] : 0;
        __syncthreads();
        s[tid] += t;
        __syncthreads();
    }
    if (tid < SCAN_BLOCKS) blocksum[tid] = s[tid] - v;  // exclusive
}

__global__ __launch_bounds__(256) void scan_c_kernel(
    const int* __restrict__ cnt, const int* __restrict__ blocksum,
    int* __restrict__ rowptr, int* __restrict__ cursor)
{
    const int idx = blockIdx.x * 256 + threadIdx.x;
    const int tid = threadIdx.x;
    const int v = (idx < NNODES) ? cnt[idx] : 0;
    __shared__ int s[256];
    s[tid] = v;
    __syncthreads();
    for (int off = 1; off < 256; off <<= 1) {
        const int t = (tid >= off) ? s[tid - off] : 0;
        __syncthreads();
        s[tid] += t;
        __syncthreads();
    }
    const int ex = s[tid] - v + blocksum[blockIdx.x];
    if (idx < NNODES) { rowptr[idx] = ex; cursor[idx] = ex; }
    if (idx == 0) rowptr[NNODES] = NEDGES;
}

// ---------------------------------------------------------------------------
// CSR build step 3: counting-sort edges by dst into (src, weight) pairs
// ---------------------------------------------------------------------------
__global__ __launch_bounds__(256) void sortbuild_kernel(
    const int* __restrict__ adj, const float* __restrict__ ew,
    int* __restrict__ cursor, uint2* __restrict__ sorted)
{
    const int e = blockIdx.x * blockDim.x + threadIdx.x;
    if (e >= NEDGES) return;
    const int dst = adj[NEDGES + e];
    const int pos = atomicAdd(&cursor[dst], 1);
    sorted[pos] = make_uint2((unsigned)adj[e], __float_as_uint(ew[e]));
}

// ---------------------------------------------------------------------------
// h0 = relu(X[N,256] @ W[128,256]^T + b)  -> bf16 out [N,128]
// One wave per 16-row strip, all 8 column tiles.
// C/D: col = n0+(lane&15), row = m0+(lane>>4)*4 + r
// ---------------------------------------------------------------------------
__global__ __launch_bounds__(256) void gemm_in_kernel(
    const float* __restrict__ X, const float* __restrict__ W,
    const float* __restrict__ bias, __hip_bfloat16* __restrict__ out)
{
    const int wave = blockIdx.x * 4 + (threadIdx.x >> 6);
    if (wave >= NNODES / 16) return;              // 3125 m-tiles
    const int lane = threadIdx.x & 63;
    const int m0 = wave << 4;
    const int ar = lane & 15;
    const int q  = lane >> 4;

    floatx4 acc[8] = {};
    #pragma unroll
    for (int k0 = 0; k0 < NF; k0 += 32) {
        const bf16x8 a = cvt8(X + (size_t)(m0 + ar) * NF + k0 + q * 8);
        #pragma unroll
        for (int t = 0; t < 8; ++t) {
            const bf16x8 b = cvt8(W + (size_t)(t * 16 + ar) * NF + k0 + q * 8);
            acc[t] = __builtin_amdgcn_mfma_f32_16x16x32_bf16(a, b, acc[t], 0, 0, 0);
        }
    }
    #pragma unroll
    for (int t = 0; t < 8; ++t) {
        const int col = t * 16 + ar;
        const float bv = bias[col];
        #pragma unroll
        for (int r = 0; r < 4; ++r) {
            float v = fmaxf(acc[t][r] + bv, 0.f);
            out[(size_t)(m0 + q * 4 + r) * NH + col] = f2bf(v);
        }
    }
}

// ---------------------------------------------------------------------------
// Gather-reduce: agg[n] = sum_{e in CSR[n]} w_e * h[src_e]   (bf16 out)
// One wave per node, 2 feats per lane, fp32 register accumulation.
// ---------------------------------------------------------------------------
__global__ __launch_bounds__(256) void gather_kernel(
    const uint2* __restrict__ sorted, const int* __restrict__ rowptr,
    const __hip_bfloat16* __restrict__ h, __hip_bfloat16* __restrict__ agg)
{
    const int node = blockIdx.x * 4 + (threadIdx.x >> 6);
    if (node >= NNODES) return;
    const int lane = threadIdx.x & 63;
    const int beg = rowptr[node];
    const int end = rowptr[node + 1];

    float a0 = 0.f, a1 = 0.f;
    const unsigned short* hb = (const unsigned short*)h;
    for (int j = beg; j < end; ++j) {
        const uint2 ev = sorted[j];                       // broadcast 8B
        const float w = __uint_as_float(ev.y);
        const unsigned raw = *(const unsigned*)(hb + (size_t)ev.x * NH + lane * 2);
        a0 += w * bits2f((unsigned short)(raw & 0xffffu));
        a1 += w * bits2f((unsigned short)(raw >> 16));
    }
    unsigned o = ((unsigned)__bfloat16_as_ushort(f2bf(a1)) << 16) |
                 (unsigned)__bfloat16_as_ushort(f2bf(a0));
    *(unsigned*)((unsigned short*)agg + (size_t)node * NH + lane * 2) = o;
}

// ---------------------------------------------------------------------------
// t = agg[N,128] @ Wrel[128,128]^T + h[N,128] @ Wroot[128,128]^T + b
// agg/h bf16, fp32 out. Fused column sum/sumsq accumulation into stats[256].
// ---------------------------------------------------------------------------
__global__ __launch_bounds__(256) void gemm_conv_kernel(
    const __hip_bfloat16* __restrict__ agg, const __hip_bfloat16* __restrict__ h,
    const float* __restrict__ Wrel, const float* __restrict__ Wroot,
    const float* __restrict__ bias, float* __restrict__ out,
    float* __restrict__ stats)
{
    const int wave = blockIdx.x * 4 + (threadIdx.x >> 6);
    const bool active = wave < NNODES / 16;
    const int lane = threadIdx.x & 63;
    const int m0 = wave << 4;
    const int ar = lane & 15;
    const int q  = lane >> 4;

    __shared__ float sst[256];
    sst[threadIdx.x] = 0.f;

    floatx4 acc[8] = {};
    if (active) {
        // chain 1: agg @ Wrel^T
        #pragma unroll
        for (int k0 = 0; k0 < NH; k0 += 32) {
            const bf16x8 a = *(const bf16x8*)(agg + (size_t)(m0 + ar) * NH + k0 + q * 8);
            #pragma unroll
            for (int t = 0; t < 8; ++t) {
                const bf16x8 b = cvt8(Wrel + (size_t)(t * 16 + ar) * NH + k0 + q * 8);
                acc[t] = __builtin_amdgcn_mfma_f32_16x16x32_bf16(a, b, acc[t], 0, 0, 0);
            }
        }
        // chain 2: h @ Wroot^T
        #pragma unroll
        for (int k0 = 0; k0 < NH; k0 += 32) {
            const bf16x8 a = *(const bf16x8*)(h + (size_t)(m0 + ar) * NH + k0 + q * 8);
            #pragma unroll
            for (int t = 0; t < 8; ++t) {
                const bf16x8 b = cvt8(Wroot + (size_t)(t * 16 + ar) * NH + k0 + q * 8);
                acc[t] = __builtin_amdgcn_mfma_f32_16x16x32_bf16(a, b, acc[t], 0, 0, 0);
            }
        }
    }
    __syncthreads();   // sst init visible; all waves present (no early return)

    if (active) {
        #pragma unroll
        for (int t = 0; t < 8; ++t) {
            const int col = t * 16 + ar;
            const float bv = bias[col];
            float s = 0.f, s2 = 0.f;
            #pragma unroll
            for (int r = 0; r < 4; ++r) {
                const float v = acc[t][r] + bv;
                out[(size_t)(m0 + q * 4 + r) * NH + col] = v;
                s += v; s2 += v * v;
            }
            // reduce across the 4 quads holding the same column
            s  += __shfl_xor(s, 16, 64);  s  += __shfl_xor(s, 32, 64);
            s2 += __shfl_xor(s2, 16, 64); s2 += __shfl_xor(s2, 32, 64);
            if (q == 0) {
                atomicAdd(&sst[col], s);
                atomicAdd(&sst[128 + col], s2);
            }
        }
    }
    __syncthreads();
    unsafeAtomicAdd(&stats[threadIdx.x], sst[threadIdx.x]);
}

// ---------------------------------------------------------------------------
// BN normalize variants
// ---------------------------------------------------------------------------
__global__ __launch_bounds__(256) void bn_relu_bf16_kernel(
    const float* __restrict__ t, const float* __restrict__ stats,
    const float* __restrict__ gamma, const float* __restrict__ beta,
    __hip_bfloat16* __restrict__ out)
{
    const size_t i = (size_t)blockIdx.x * blockDim.x + threadIdx.x;  // exact grid
    const int c = (int)(i & (NH - 1));
    const float inv_n = 1.0f / (float)NNODES;
    const float mu = stats[c] * inv_n;
    const float var = stats[128 + c] * inv_n - mu * mu;
    const float rs = rsqrtf(var + BN_EPS);
    float v = (t[i] - mu) * rs * gamma[c] + beta[c];
    out[i] = f2bf(fmaxf(v, 0.f));
}

__global__ __launch_bounds__(256) void bn_f32_kernel(
    const float* __restrict__ t, const float* __restrict__ stats,
    const float* __restrict__ gamma, const float* __restrict__ beta,
    float* __restrict__ out)
{
    const size_t i = (size_t)blockIdx.x * blockDim.x + threadIdx.x;
    const int c = (int)(i & (NH - 1));
    const float inv_n = 1.0f / (float)NNODES;
    const float mu = stats[c] * inv_n;
    const float var = stats[128 + c] * inv_n - mu * mu;
    const float rs = rsqrtf(var + BN_EPS);
    out[i] = (t[i] - mu) * rs * gamma[c] + beta[c];
}

// ---------------------------------------------------------------------------

extern "C" void kernel_launch(void* const* d_in, const int* in_sizes, int n_in,
                              void* d_out, int out_size, void* d_ws, size_t ws_size,
                              hipStream_t stream)
{
    const float* x    = (const float*)d_in[0];
    const int*   adj  = (const int*)d_in[1];
    const float* ew   = (const float*)d_in[2];
    const float* W_in = (const float*)d_in[3];
    const float* b_in = (const float*)d_in[4];
    const float* W1r  = (const float*)d_in[5];
    const float* b1   = (const float*)d_in[6];
    const float* W1o  = (const float*)d_in[7];
    const float* W2r  = (const float*)d_in[8];
    const float* b2   = (const float*)d_in[9];
    const float* W2o  = (const float*)d_in[10];
    const float* gmm  = (const float*)d_in[11];
    const float* bta  = (const float*)d_in[12];
    float* out = (float*)d_out;          // fp32 output [N, NH]
    float* t   = (float*)d_out;          // pre-BN conv result lives in d_out

    char* ws = (char*)d_ws;
    __hip_bfloat16* h0  = (__hip_bfloat16*)ws; ws += (size_t)NNODES * NH * 2;  // 12.8 MB
    __hip_bfloat16* h1  = (__hip_bfloat16*)ws; ws += (size_t)NNODES * NH * 2;  // 12.8 MB
    __hip_bfloat16* agg = (__hip_bfloat16*)ws; ws += (size_t)NNODES * NH * 2;  // 12.8 MB
    uint2*          sorted = (uint2*)ws;       ws += (size_t)NEDGES * 8;       // 6.4 MB
    int*            rowptr = (int*)ws;         ws += (NNODES + 16) * 4;
    int*            cnt    = (int*)ws;         ws += NNODES * 4;
    int*            cursor = (int*)ws;         ws += NNODES * 4;
    int*            bsum   = (int*)ws;         ws += SCAN_BLOCKS * 4;
    float*          st     = (float*)ws;       ws += 256 * 4;

    const int gemm_blocks = (NNODES / 16 + 3) / 4;              // 782
    const int edge_blocks = (NEDGES + 255) / 256;               // 3125
    const int node_blocks = (NNODES + 3) / 4;                   // 12500
    const int bn_blocks   = (NNODES * NH) / 256;                // 25000

    // ---- CSR build (adjacency is shared by both layers) ----
    hipMemsetAsync(cnt, 0, NNODES * 4, stream);
    hist_kernel<<<edge_blocks, 256, 0, stream>>>(adj, cnt);
    scan_a_kernel<<<SCAN_BLOCKS, 256, 0, stream>>>(cnt, bsum);
    scan_b_kernel<<<1, 256, 0, stream>>>(bsum);
    scan_c_kernel<<<SCAN_BLOCKS, 256, 0, stream>>>(cnt, bsum, rowptr, cursor);
    sortbuild_kernel<<<edge_blocks, 256, 0, stream>>>(adj, ew, cursor, sorted);

    // ---- layer 1 ----
    hipMemsetAsync(st, 0, 256 * 4, stream);
    gemm_in_kernel<<<gemm_blocks, 256, 0, stream>>>(x, W_in, b_in, h0);
    gather_kernel<<<node_blocks, 256, 0, stream>>>(sorted, rowptr, h0, agg);
    gemm_conv_kernel<<<gemm_blocks, 256, 0, stream>>>(agg, h0, W1r, W1o, b1, t, st);
    bn_relu_bf16_kernel<<<bn_blocks, 256, 0, stream>>>(t, st, gmm, bta, h1);

    // ---- layer 2 ----
    hipMemsetAsync(st, 0, 256 * 4, stream);
    gather_kernel<<<node_blocks, 256, 0, stream>>>(sorted, rowptr, h1, agg);
    gemm_conv_kernel<<<gemm_blocks, 256, 0, stream>>>(agg, h1, W2r, W2o, b2, t, st);
    bn_f32_kernel<<<bn_blocks, 256, 0, stream>>>(t, st, gmm, bta, out);
}

// Round 5
// 392.046 us; speedup vs baseline: 7.9032x; 1.5305x over previous
//
#include <hip/hip_runtime.h>
#include <hip/hip_bf16.h>

// Problem sizes (fixed by the reference)
#define NNODES 50000   // 3125 * 16 -> exact 16-row MFMA tiles
#define NEDGES 800000
#define NF 256         // input features
#define NH 128         // hidden
#define BN_EPS 1e-5f
#define SCAN_BLOCKS ((NNODES + 255) / 256)   // 196
#define MTILES (NNODES / 16)                 // 3125
#define GEMM_BLOCKS 512                      // 2048 waves; wave = (strip % 1024, half)

typedef __attribute__((ext_vector_type(8))) __bf16 bf16x8;  // MFMA A/B frag (4 VGPRs)
typedef __attribute__((ext_vector_type(4))) float floatx4;  // MFMA C/D frag

__device__ __forceinline__ __hip_bfloat16 f2bf(float f) { return __float2bfloat16(f); }
__device__ __forceinline__ float bits2f(unsigned short b) {
    union { unsigned u; float f; } u; u.u = ((unsigned)b) << 16; return u.f;
}

// load 8 consecutive fp32, round to bf16x8 MFMA fragment
__device__ __forceinline__ bf16x8 cvt8(const float* __restrict__ p) {
    floatx4 a0 = *(const floatx4*)p;
    floatx4 a1 = *(const floatx4*)(p + 4);
    bf16x8 r;
    r[0] = (__bf16)a0[0]; r[1] = (__bf16)a0[1]; r[2] = (__bf16)a0[2]; r[3] = (__bf16)a0[3];
    r[4] = (__bf16)a1[0]; r[5] = (__bf16)a1[1]; r[6] = (__bf16)a1[2]; r[7] = (__bf16)a1[3];
    return r;
}

// ---------------------------------------------------------------------------
// One-shot weight conversion fp32 -> bf16 into contiguous wbf:
// [W_in 32768 | W1r 16384 | W1o 16384 | W2r 16384 | W2o 16384]
// ---------------------------------------------------------------------------
__global__ __launch_bounds__(256) void convert_w_kernel(
    const float* __restrict__ W_in, const float* __restrict__ W1r,
    const float* __restrict__ W1o, const float* __restrict__ W2r,
    const float* __restrict__ W2o, __hip_bfloat16* __restrict__ wbf)
{
    const int i = blockIdx.x * 256 + threadIdx.x;   // grid sized exactly 98304
    const float* src; int off;
    if (i < 32768)      { src = W_in; off = i; }
    else if (i < 49152) { src = W1r;  off = i - 32768; }
    else if (i < 65536) { src = W1o;  off = i - 49152; }
    else if (i < 81920) { src = W2r;  off = i - 65536; }
    else                { src = W2o;  off = i - 81920; }
    wbf[i] = f2bf(src[off]);
}

// ---------------------------------------------------------------------------
// CSR build step 1: per-dst edge counts
// ---------------------------------------------------------------------------
__global__ __launch_bounds__(256) void hist_kernel(
    const int* __restrict__ adj, int* __restrict__ cnt)
{
    const int e = blockIdx.x * blockDim.x + threadIdx.x;
    if (e >= NEDGES) return;
    atomicAdd(&cnt[adj[NEDGES + e]], 1);
}

// ---------------------------------------------------------------------------
// CSR build step 2: three-phase exclusive scan (coalesced, multi-block)
// ---------------------------------------------------------------------------
__global__ __launch_bounds__(256) void scan_a_kernel(
    const int* __restrict__ cnt, int* __restrict__ blocksum)
{
    const int idx = blockIdx.x * 256 + threadIdx.x;
    int v = (idx < NNODES) ? cnt[idx] : 0;
    __shared__ int red[256];
    red[threadIdx.x] = v;
    __syncthreads();
    for (int off = 128; off > 0; off >>= 1) {
        if (threadIdx.x < off) red[threadIdx.x] += red[threadIdx.x + off];
        __syncthreads();
    }
    if (threadIdx.x == 0) blocksum[blockIdx.x] = red[0];
}

__global__ __launch_bounds__(256) void scan_b_kernel(int* __restrict__ blocksum)
{
    __shared__ int s[256];
    const int tid = threadIdx.x;
    const int v = (tid < SCAN_BLOCKS) ? blocksum[tid] : 0;
    s[tid] = v;
    __syncthreads();
    for (int off = 1; off < 256; off <<= 1) {
        const int t = (tid >= off) ? s[tid - off] : 0;
        __syncthreads();
        s[tid] += t;
        __syncthreads();
    }
    if (tid < SCAN_BLOCKS) blocksum[tid] = s[tid] - v;  // exclusive
}

__global__ __launch_bounds__(256) void scan_c_kernel(
    const int* __restrict__ cnt, const int* __restrict__ blocksum,
    int* __restrict__ rowptr, int* __restrict__ cursor)
{
    const int idx = blockIdx.x * 256 + threadIdx.x;
    const int tid = threadIdx.x;
    const int v = (idx < NNODES) ? cnt[idx] : 0;
    __shared__ int s[256];
    s[tid] = v;
    __syncthreads();
    for (int off = 1; off < 256; off <<= 1) {
        const int t = (tid >= off) ? s[tid - off] : 0;
        __syncthreads();
        s[tid] += t;
        __syncthreads();
    }
    const int ex = s[tid] - v + blocksum[blockIdx.x];
    if (idx < NNODES) { rowptr[idx] = ex; cursor[idx] = ex; }
    if (idx == 0) rowptr[NNODES] = NEDGES;
}

// ---------------------------------------------------------------------------
// CSR build step 3: counting-sort edges by dst into (src, weight) pairs
// ---------------------------------------------------------------------------
__global__ __launch_bounds__(256) void sortbuild_kernel(
    const int* __restrict__ adj, const float* __restrict__ ew,
    int* __restrict__ cursor, uint2* __restrict__ sorted)
{
    const int e = blockIdx.x * blockDim.x + threadIdx.x;
    if (e >= NEDGES) return;
    const int dst = adj[NEDGES + e];
    const int pos = atomicAdd(&cursor[dst], 1);
    sorted[pos] = make_uint2((unsigned)adj[e], __float_as_uint(ew[e]));
}

// ---------------------------------------------------------------------------
// h0 = relu(X[N,256] @ W[128,256]^T + b) -> bf16. Register-resident weights:
// wave owns column-half (4 tiles x 8 ksteps = 128 VGPRs of B-frags), loops strips.
// C/D: col = tile*16+(lane&15), row = m0+(lane>>4)*4 + r
// ---------------------------------------------------------------------------
__global__ __launch_bounds__(256, 2) void gemm_in_kernel(
    const float* __restrict__ X, const __hip_bfloat16* __restrict__ W,
    const float* __restrict__ bias, __hip_bfloat16* __restrict__ out)
{
    const int waveG = blockIdx.x * 4 + (threadIdx.x >> 6);  // 0..2047
    const int lane = threadIdx.x & 63;
    const int half = waveG & 1;
    const int ar = lane & 15;
    const int q  = lane >> 4;

    bf16x8 bw[4][8];
    float bv[4];
    #pragma unroll
    for (int t = 0; t < 4; ++t) {
        const int row = half * 64 + t * 16 + ar;
        bv[t] = bias[row];
        #pragma unroll
        for (int k = 0; k < 8; ++k)
            bw[t][k] = *(const bf16x8*)(W + (size_t)row * NF + k * 32 + q * 8);
    }

    for (int strip = waveG >> 1; strip < MTILES; strip += GEMM_BLOCKS * 2) {
        const int m0 = strip << 4;
        floatx4 acc[4] = {};
        #pragma unroll
        for (int k = 0; k < 8; ++k) {
            const bf16x8 a = cvt8(X + (size_t)(m0 + ar) * NF + k * 32 + q * 8);
            #pragma unroll
            for (int t = 0; t < 4; ++t)
                acc[t] = __builtin_amdgcn_mfma_f32_16x16x32_bf16(a, bw[t][k], acc[t], 0, 0, 0);
        }
        #pragma unroll
        for (int t = 0; t < 4; ++t) {
            const int col = half * 64 + t * 16 + ar;
            #pragma unroll
            for (int r = 0; r < 4; ++r) {
                const float v = fmaxf(acc[t][r] + bv[t], 0.f);
                out[(size_t)(m0 + q * 4 + r) * NH + col] = f2bf(v);
            }
        }
    }
}

// ---------------------------------------------------------------------------
// Gather-reduce: agg[n] = sum_{e in CSR[n]} w_e * h[src_e]   (bf16 out)
// One wave per node, 2 feats/lane, 4-way edge unroll (independent loads).
// ---------------------------------------------------------------------------
__global__ __launch_bounds__(256) void gather_kernel(
    const uint2* __restrict__ sorted, const int* __restrict__ rowptr,
    const __hip_bfloat16* __restrict__ h, __hip_bfloat16* __restrict__ agg)
{
    const int node = blockIdx.x * 4 + (threadIdx.x >> 6);
    if (node >= NNODES) return;
    const int lane = threadIdx.x & 63;
    const int beg = rowptr[node];
    const int end = rowptr[node + 1];
    const unsigned short* hb = (const unsigned short*)h;

    float p0 = 0.f, p1 = 0.f, q0 = 0.f, q1 = 0.f;
    float r0 = 0.f, r1 = 0.f, s0 = 0.f, s1 = 0.f;

    int j = beg;
    if ((j & 1) && j < end) {  // align to 16B for uint4 loads
        const uint2 ev = sorted[j++];
        const float w = __uint_as_float(ev.y);
        const unsigned raw = *(const unsigned*)(hb + (size_t)ev.x * NH + lane * 2);
        p0 += w * bits2f((unsigned short)(raw & 0xffffu));
        p1 += w * bits2f((unsigned short)(raw >> 16));
    }
    for (; j + 4 <= end; j += 4) {
        const uint4 e01 = *(const uint4*)(sorted + j);
        const uint4 e23 = *(const uint4*)(sorted + j + 2);
        const unsigned ra = *(const unsigned*)(hb + (size_t)e01.x * NH + lane * 2);
        const unsigned rb = *(const unsigned*)(hb + (size_t)e01.z * NH + lane * 2);
        const unsigned rc = *(const unsigned*)(hb + (size_t)e23.x * NH + lane * 2);
        const unsigned rd = *(const unsigned*)(hb + (size_t)e23.z * NH + lane * 2);
        const float wa = __uint_as_float(e01.y), wb = __uint_as_float(e01.w);
        const float wc = __uint_as_float(e23.y), wd = __uint_as_float(e23.w);
        p0 += wa * bits2f((unsigned short)(ra & 0xffffu));
        p1 += wa * bits2f((unsigned short)(ra >> 16));
        q0 += wb * bits2f((unsigned short)(rb & 0xffffu));
        q1 += wb * bits2f((unsigned short)(rb >> 16));
        r0 += wc * bits2f((unsigned short)(rc & 0xffffu));
        r1 += wc * bits2f((unsigned short)(rc >> 16));
        s0 += wd * bits2f((unsigned short)(rd & 0xffffu));
        s1 += wd * bits2f((unsigned short)(rd >> 16));
    }
    for (; j < end; ++j) {
        const uint2 ev = sorted[j];
        const float w = __uint_as_float(ev.y);
        const unsigned raw = *(const unsigned*)(hb + (size_t)ev.x * NH + lane * 2);
        p0 += w * bits2f((unsigned short)(raw & 0xffffu));
        p1 += w * bits2f((unsigned short)(raw >> 16));
    }
    const float a0 = (p0 + q0) + (r0 + s0);
    const float a1 = (p1 + q1) + (r1 + s1);
    unsigned o = ((unsigned)__bfloat16_as_ushort(f2bf(a1)) << 16) |
                 (unsigned)__bfloat16_as_ushort(f2bf(a0));
    *(unsigned*)((unsigned short*)agg + (size_t)node * NH + lane * 2) = o;
}

// ---------------------------------------------------------------------------
// t = agg @ Wrel^T + h @ Wroot^T + b   (bf16 in, fp32 out)
// Register-resident weights (2 chains x 4 tiles x 4 ksteps = 128 VGPRs).
// Fused column sum/sumsq -> per-block partial[256].
// ---------------------------------------------------------------------------
__global__ __launch_bounds__(256, 2) void gemm_conv_kernel(
    const __hip_bfloat16* __restrict__ agg, const __hip_bfloat16* __restrict__ h,
    const __hip_bfloat16* __restrict__ Wrel, const __hip_bfloat16* __restrict__ Wroot,
    const float* __restrict__ bias, float* __restrict__ out,
    float* __restrict__ partial)
{
    const int waveG = blockIdx.x * 4 + (threadIdx.x >> 6);  // 0..2047
    const int lane = threadIdx.x & 63;
    const int half = waveG & 1;
    const int ar = lane & 15;
    const int q  = lane >> 4;

    bf16x8 brel[4][4], brt[4][4];
    float bv[4];
    #pragma unroll
    for (int t = 0; t < 4; ++t) {
        const int row = half * 64 + t * 16 + ar;
        bv[t] = bias[row];
        #pragma unroll
        for (int k = 0; k < 4; ++k) {
            brel[t][k] = *(const bf16x8*)(Wrel + (size_t)row * NH + k * 32 + q * 8);
            brt[t][k]  = *(const bf16x8*)(Wroot + (size_t)row * NH + k * 32 + q * 8);
        }
    }

    float s1[4] = {}, s2[4] = {};

    for (int strip = waveG >> 1; strip < MTILES; strip += GEMM_BLOCKS * 2) {
        const int m0 = strip << 4;
        floatx4 acc[4] = {};
        #pragma unroll
        for (int k = 0; k < 4; ++k) {
            const bf16x8 a = *(const bf16x8*)(agg + (size_t)(m0 + ar) * NH + k * 32 + q * 8);
            #pragma unroll
            for (int t = 0; t < 4; ++t)
                acc[t] = __builtin_amdgcn_mfma_f32_16x16x32_bf16(a, brel[t][k], acc[t], 0, 0, 0);
        }
        #pragma unroll
        for (int k = 0; k < 4; ++k) {
            const bf16x8 a = *(const bf16x8*)(h + (size_t)(m0 + ar) * NH + k * 32 + q * 8);
            #pragma unroll
            for (int t = 0; t < 4; ++t)
                acc[t] = __builtin_amdgcn_mfma_f32_16x16x32_bf16(a, brt[t][k], acc[t], 0, 0, 0);
        }
        #pragma unroll
        for (int t = 0; t < 4; ++t) {
            const int col = half * 64 + t * 16 + ar;
            #pragma unroll
            for (int r = 0; r < 4; ++r) {
                const float v = acc[t][r] + bv[t];
                out[(size_t)(m0 + q * 4 + r) * NH + col] = v;
                s1[t] += v; s2[t] += v * v;
            }
        }
    }

    __shared__ float sst[256];
    sst[threadIdx.x] = 0.f;
    __syncthreads();
    #pragma unroll
    for (int t = 0; t < 4; ++t) {
        float a = s1[t], b = s2[t];
        a += __shfl_xor(a, 16, 64); a += __shfl_xor(a, 32, 64);
        b += __shfl_xor(b, 16, 64); b += __shfl_xor(b, 32, 64);
        if (q == 0) {
            const int col = half * 64 + t * 16 + ar;
            atomicAdd(&sst[col], a);
            atomicAdd(&sst[128 + col], b);
        }
    }
    __syncthreads();
    partial[blockIdx.x * 256 + threadIdx.x] = sst[threadIdx.x];
}

// ---------------------------------------------------------------------------
// stats[c] = sum over blocks of partial[b][c]
// ---------------------------------------------------------------------------
__global__ __launch_bounds__(256) void reduce_stats_kernel(
    const float* __restrict__ partial, float* __restrict__ stats)
{
    const int tid = threadIdx.x;
    float a = 0.f, b = 0.f, c = 0.f, d = 0.f;
    for (int blk = 0; blk < GEMM_BLOCKS; blk += 4) {
        a += partial[(blk + 0) * 256 + tid];
        b += partial[(blk + 1) * 256 + tid];
        c += partial[(blk + 2) * 256 + tid];
        d += partial[(blk + 3) * 256 + tid];
    }
    stats[tid] = (a + b) + (c + d);
}

// ---------------------------------------------------------------------------
// BN normalize variants
// ---------------------------------------------------------------------------
__global__ __launch_bounds__(256) void bn_relu_bf16_kernel(
    const float* __restrict__ t, const float* __restrict__ stats,
    const float* __restrict__ gamma, const float* __restrict__ beta,
    __hip_bfloat16* __restrict__ out)
{
    const size_t i = (size_t)blockIdx.x * blockDim.x + threadIdx.x;  // exact grid
    const int c = (int)(i & (NH - 1));
    const float inv_n = 1.0f / (float)NNODES;
    const float mu = stats[c] * inv_n;
    const float var = stats[128 + c] * inv_n - mu * mu;
    const float rs = rsqrtf(var + BN_EPS);
    float v = (t[i] - mu) * rs * gamma[c] + beta[c];
    out[i] = f2bf(fmaxf(v, 0.f));
}

__global__ __launch_bounds__(256) void bn_f32_kernel(
    const float* __restrict__ t, const float* __restrict__ stats,
    const float* __restrict__ gamma, const float* __restrict__ beta,
    float* __restrict__ out)
{
    const size_t i = (size_t)blockIdx.x * blockDim.x + threadIdx.x;
    const int c = (int)(i & (NH - 1));
    const float inv_n = 1.0f / (float)NNODES;
    const float mu = stats[c] * inv_n;
    const float var = stats[128 + c] * inv_n - mu * mu;
    const float rs = rsqrtf(var + BN_EPS);
    out[i] = (t[i] - mu) * rs * gamma[c] + beta[c];
}

// ---------------------------------------------------------------------------

extern "C" void kernel_launch(void* const* d_in, const int* in_sizes, int n_in,
                              void* d_out, int out_size, void* d_ws, size_t ws_size,
                              hipStream_t stream)
{
    const float* x    = (const float*)d_in[0];
    const int*   adj  = (const int*)d_in[1];
    const float* ew   = (const float*)d_in[2];
    const float* W_in = (const float*)d_in[3];
    const float* b_in = (const float*)d_in[4];
    const float* W1r  = (const float*)d_in[5];
    const float* b1   = (const float*)d_in[6];
    const float* W1o  = (const float*)d_in[7];
    const float* W2r  = (const float*)d_in[8];
    const float* b2   = (const float*)d_in[9];
    const float* W2o  = (const float*)d_in[10];
    const float* gmm  = (const float*)d_in[11];
    const float* bta  = (const float*)d_in[12];
    float* out = (float*)d_out;          // fp32 output [N, NH]
    float* t   = (float*)d_out;          // pre-BN conv result lives in d_out

    char* ws = (char*)d_ws;
    __hip_bfloat16* h0  = (__hip_bfloat16*)ws; ws += (size_t)NNODES * NH * 2;  // 12.8 MB
    __hip_bfloat16* h1  = (__hip_bfloat16*)ws; ws += (size_t)NNODES * NH * 2;  // 12.8 MB
    __hip_bfloat16* agg = (__hip_bfloat16*)ws; ws += (size_t)NNODES * NH * 2;  // 12.8 MB
    uint2*          sorted = (uint2*)ws;       ws += (size_t)NEDGES * 8;       // 6.4 MB
    int*            rowptr = (int*)ws;         ws += (NNODES + 16) * 4;
    int*            cnt    = (int*)ws;         ws += NNODES * 4;
    int*            cursor = (int*)ws;         ws += NNODES * 4;
    int*            bsum   = (int*)ws;         ws += SCAN_BLOCKS * 4;
    __hip_bfloat16* wbf    = (__hip_bfloat16*)ws; ws += 98304 * 2;             // 192 KB
    float*          partial = (float*)ws;      ws += GEMM_BLOCKS * 256 * 4;    // 512 KB
    float*          st     = (float*)ws;       ws += 256 * 4;

    const __hip_bfloat16* Wb_in = wbf;
    const __hip_bfloat16* Wb1r  = wbf + 32768;
    const __hip_bfloat16* Wb1o  = wbf + 49152;
    const __hip_bfloat16* Wb2r  = wbf + 65536;
    const __hip_bfloat16* Wb2o  = wbf + 81920;

    const int edge_blocks = (NEDGES + 255) / 256;               // 3125
    const int node_blocks = (NNODES + 3) / 4;                   // 12500
    const int bn_blocks   = (NNODES * NH) / 256;                // 25000

    // ---- prep: weight conversion + CSR build ----
    convert_w_kernel<<<98304 / 256, 256, 0, stream>>>(W_in, W1r, W1o, W2r, W2o, wbf);
    hipMemsetAsync(cnt, 0, NNODES * 4, stream);
    hist_kernel<<<edge_blocks, 256, 0, stream>>>(adj, cnt);
    scan_a_kernel<<<SCAN_BLOCKS, 256, 0, stream>>>(cnt, bsum);
    scan_b_kernel<<<1, 256, 0, stream>>>(bsum);
    scan_c_kernel<<<SCAN_BLOCKS, 256, 0, stream>>>(cnt, bsum, rowptr, cursor);
    sortbuild_kernel<<<edge_blocks, 256, 0, stream>>>(adj, ew, cursor, sorted);

    // ---- layer 1 ----
    gemm_in_kernel<<<GEMM_BLOCKS, 256, 0, stream>>>(x, Wb_in, b_in, h0);
    gather_kernel<<<node_blocks, 256, 0, stream>>>(sorted, rowptr, h0, agg);
    gemm_conv_kernel<<<GEMM_BLOCKS, 256, 0, stream>>>(agg, h0, Wb1r, Wb1o, b1, t, partial);
    reduce_stats_kernel<<<1, 256, 0, stream>>>(partial, st);
    bn_relu_bf16_kernel<<<bn_blocks, 256, 0, stream>>>(t, st, gmm, bta, h1);

    // ---- layer 2 ----
    gather_kernel<<<node_blocks, 256, 0, stream>>>(sorted, rowptr, h1, agg);
    gemm_conv_kernel<<<GEMM_BLOCKS, 256, 0, stream>>>(agg, h1, Wb2r, Wb2o, b2, t, partial);
    reduce_stats_kernel<<<1, 256, 0, stream>>>(partial, st);
    bn_f32_kernel<<<bn_blocks, 256, 0, stream>>>(t, st, gmm, bta, out);
}

// Round 6
// 337.274 us; speedup vs baseline: 9.1866x; 1.1624x over previous
//
#include <hip/hip_runtime.h>
#include <hip/hip_bf16.h>

// Problem sizes (fixed by the reference)
#define NNODES 50000   // 3125 * 16 -> exact 16-row MFMA tiles
#define NEDGES 800000
#define NF 256         // input features
#define NH 128         // hidden
#define BN_EPS 1e-5f
#define MTILES (NNODES / 16)                 // 3125
#define GEMM_BLOCKS 512                      // 2048 waves; wave = (strip, half)
#define NBUCKETS 196                         // ceil(NNODES / 256)
#define BCAP 4608                            // bucket capacity: mean 4096 + 8 sigma
#define SCAT_BLOCKS ((NEDGES + 2047) / 2048) // 391

typedef __attribute__((ext_vector_type(8))) __bf16 bf16x8;  // MFMA A/B frag (4 VGPRs)
typedef __attribute__((ext_vector_type(4))) float floatx4;  // MFMA C/D frag

__device__ __forceinline__ __hip_bfloat16 f2bf(float f) { return __float2bfloat16(f); }
__device__ __forceinline__ float bits2f(unsigned short b) {
    union { unsigned u; float f; } u; u.u = ((unsigned)b) << 16; return u.f;
}

// load 8 consecutive fp32, round to bf16x8 MFMA fragment
__device__ __forceinline__ bf16x8 cvt8(const float* __restrict__ p) {
    floatx4 a0 = *(const floatx4*)p;
    floatx4 a1 = *(const floatx4*)(p + 4);
    bf16x8 r;
    r[0] = (__bf16)a0[0]; r[1] = (__bf16)a0[1]; r[2] = (__bf16)a0[2]; r[3] = (__bf16)a0[3];
    r[4] = (__bf16)a1[0]; r[5] = (__bf16)a1[1]; r[6] = (__bf16)a1[2]; r[7] = (__bf16)a1[3];
    return r;
}

// ---------------------------------------------------------------------------
// One-shot weight conversion fp32 -> bf16 into contiguous wbf:
// [W_in 32768 | W1r 16384 | W1o 16384 | W2r 16384 | W2o 16384]
// Block 0 also initializes the bucket cursors to their fixed-stride bases.
// ---------------------------------------------------------------------------
__global__ __launch_bounds__(256) void convert_w_kernel(
    const float* __restrict__ W_in, const float* __restrict__ W1r,
    const float* __restrict__ W1o, const float* __restrict__ W2r,
    const float* __restrict__ W2o, __hip_bfloat16* __restrict__ wbf,
    int* __restrict__ gcursor)
{
    const int i = blockIdx.x * 256 + threadIdx.x;   // grid sized exactly 98304
    if (blockIdx.x == 0 && threadIdx.x < NBUCKETS)
        gcursor[threadIdx.x] = threadIdx.x * BCAP;
    const float* src; int off;
    if (i < 32768)      { src = W_in; off = i; }
    else if (i < 49152) { src = W1r;  off = i - 32768; }
    else if (i < 65536) { src = W1o;  off = i - 49152; }
    else if (i < 81920) { src = W2r;  off = i - 65536; }
    else                { src = W2o;  off = i - 81920; }
    wbf[i] = f2bf(src[off]);
}

// ---------------------------------------------------------------------------
// CSR level 1: bucket edges by dst>>8 into fixed-stride regions.
// Per-block LDS counting + one global atomic per touched bucket.
// ---------------------------------------------------------------------------
__global__ __launch_bounds__(256) void bucket_scatter_kernel(
    const int* __restrict__ adj, const float* __restrict__ ew,
    int* __restrict__ gcursor, uint2* __restrict__ pairbuf,
    unsigned char* __restrict__ nodebuf)
{
    __shared__ int cnt[NBUCKETS];
    __shared__ int base[NBUCKETS];
    const int tid = threadIdx.x;
    if (tid < NBUCKETS) cnt[tid] = 0;
    __syncthreads();
    const int e0 = blockIdx.x * 2048;
    #pragma unroll
    for (int i = 0; i < 8; ++i) {
        const int e = e0 + i * 256 + tid;
        if (e < NEDGES) atomicAdd(&cnt[adj[NEDGES + e] >> 8], 1);
    }
    __syncthreads();
    if (tid < NBUCKETS) {
        base[tid] = atomicAdd(&gcursor[tid], cnt[tid]);
        cnt[tid] = 0;
    }
    __syncthreads();
    #pragma unroll
    for (int i = 0; i < 8; ++i) {
        const int e = e0 + i * 256 + tid;
        if (e >= NEDGES) continue;
        const int dst = adj[NEDGES + e];
        const int b = dst >> 8;
        const int off = atomicAdd(&cnt[b], 1);
        const int slot = base[b] + off;
        if (slot < (b + 1) * BCAP) {          // overflow guard (P ~ 1e-10)
            pairbuf[slot] = make_uint2((unsigned)adj[e], __float_as_uint(ew[e]));
            nodebuf[slot] = (unsigned char)(dst & 255);
        }
    }
}

// ---------------------------------------------------------------------------
// CSR level 2: one block per bucket; sort ~4096 edges by node (LDS counting
// sort over 256 nodes), write final (src,w) pairs + rowptr/rowend.
// ---------------------------------------------------------------------------
__global__ __launch_bounds__(256) void bucket_sort_kernel(
    const int* __restrict__ gcursor, const uint2* __restrict__ pairbuf,
    const unsigned char* __restrict__ nodebuf, uint2* __restrict__ sorted,
    int* __restrict__ rowptr, int* __restrict__ rowend)
{
    const int b = blockIdx.x;
    const int tid = threadIdx.x;
    const int capbase = b * BCAP;
    int n = gcursor[b] - capbase;
    if (n > BCAP) n = BCAP;

    __shared__ int cnt[256];
    __shared__ int s[256];
    cnt[tid] = 0;
    __syncthreads();
    for (int j = tid; j < n; j += 256)
        atomicAdd(&cnt[nodebuf[capbase + j]], 1);
    __syncthreads();
    const int v = cnt[tid];
    s[tid] = v;
    __syncthreads();
    for (int off = 1; off < 256; off <<= 1) {
        const int t = (tid >= off) ? s[tid - off] : 0;
        __syncthreads();
        s[tid] += t;
        __syncthreads();
    }
    const int excl = s[tid] - v;
    const int node = b * 256 + tid;
    if (node < NNODES) {
        rowptr[node] = capbase + excl;
        rowend[node] = capbase + excl + v;
    }
    cnt[tid] = excl;                          // reuse as scatter cursor
    __syncthreads();
    for (int j = tid; j < n; j += 256) {
        const int nd = nodebuf[capbase + j];
        const int pos = atomicAdd(&cnt[nd], 1);
        sorted[capbase + pos] = pairbuf[capbase + j];
    }
}

// ---------------------------------------------------------------------------
// h0 = relu(X[N,256] @ W[128,256]^T + b) -> bf16. Register-resident weights:
// wave owns column-half (4 tiles x 8 ksteps = 128 VGPRs of B-frags), loops strips.
// C/D: col = tile*16+(lane&15), row = m0+(lane>>4)*4 + r
// ---------------------------------------------------------------------------
__global__ __launch_bounds__(256, 2) void gemm_in_kernel(
    const float* __restrict__ X, const __hip_bfloat16* __restrict__ W,
    const float* __restrict__ bias, __hip_bfloat16* __restrict__ out)
{
    const int waveG = blockIdx.x * 4 + (threadIdx.x >> 6);  // 0..2047
    const int lane = threadIdx.x & 63;
    const int half = waveG & 1;
    const int ar = lane & 15;
    const int q  = lane >> 4;

    bf16x8 bw[4][8];
    float bv[4];
    #pragma unroll
    for (int t = 0; t < 4; ++t) {
        const int row = half * 64 + t * 16 + ar;
        bv[t] = bias[row];
        #pragma unroll
        for (int k = 0; k < 8; ++k)
            bw[t][k] = *(const bf16x8*)(W + (size_t)row * NF + k * 32 + q * 8);
    }

    for (int strip = waveG >> 1; strip < MTILES; strip += GEMM_BLOCKS * 2) {
        const int m0 = strip << 4;
        floatx4 acc[4] = {};
        #pragma unroll
        for (int k = 0; k < 8; ++k) {
            const bf16x8 a = cvt8(X + (size_t)(m0 + ar) * NF + k * 32 + q * 8);
            #pragma unroll
            for (int t = 0; t < 4; ++t)
                acc[t] = __builtin_amdgcn_mfma_f32_16x16x32_bf16(a, bw[t][k], acc[t], 0, 0, 0);
        }
        #pragma unroll
        for (int t = 0; t < 4; ++t) {
            const int col = half * 64 + t * 16 + ar;
            #pragma unroll
            for (int r = 0; r < 4; ++r) {
                const float v = fmaxf(acc[t][r] + bv[t], 0.f);
                out[(size_t)(m0 + q * 4 + r) * NH + col] = f2bf(v);
            }
        }
    }
}

// ---------------------------------------------------------------------------
// Gather-reduce: agg[n] = sum_{e in CSR[n]} w_e * h[src_e]   (bf16 out)
// One wave per node, 2 feats/lane, 4-way edge unroll (independent loads).
// ---------------------------------------------------------------------------
__global__ __launch_bounds__(256) void gather_kernel(
    const uint2* __restrict__ sorted, const int* __restrict__ rowptr,
    const int* __restrict__ rowend,
    const __hip_bfloat16* __restrict__ h, __hip_bfloat16* __restrict__ agg)
{
    const int node = blockIdx.x * 4 + (threadIdx.x >> 6);
    if (node >= NNODES) return;
    const int lane = threadIdx.x & 63;
    const int beg = rowptr[node];
    const int end = rowend[node];
    const unsigned short* hb = (const unsigned short*)h;

    float p0 = 0.f, p1 = 0.f, q0 = 0.f, q1 = 0.f;
    float r0 = 0.f, r1 = 0.f, s0 = 0.f, s1 = 0.f;

    int j = beg;
    if ((j & 1) && j < end) {  // align to 16B for uint4 loads
        const uint2 ev = sorted[j++];
        const float w = __uint_as_float(ev.y);
        const unsigned raw = *(const unsigned*)(hb + (size_t)ev.x * NH + lane * 2);
        p0 += w * bits2f((unsigned short)(raw & 0xffffu));
        p1 += w * bits2f((unsigned short)(raw >> 16));
    }
    for (; j + 4 <= end; j += 4) {
        const uint4 e01 = *(const uint4*)(sorted + j);
        const uint4 e23 = *(const uint4*)(sorted + j + 2);
        const unsigned ra = *(const unsigned*)(hb + (size_t)e01.x * NH + lane * 2);
        const unsigned rb = *(const unsigned*)(hb + (size_t)e01.z * NH + lane * 2);
        const unsigned rc = *(const unsigned*)(hb + (size_t)e23.x * NH + lane * 2);
        const unsigned rd = *(const unsigned*)(hb + (size_t)e23.z * NH + lane * 2);
        const float wa = __uint_as_float(e01.y), wb = __uint_as_float(e01.w);
        const float wc = __uint_as_float(e23.y), wd = __uint_as_float(e23.w);
        p0 += wa * bits2f((unsigned short)(ra & 0xffffu));
        p1 += wa * bits2f((unsigned short)(ra >> 16));
        q0 += wb * bits2f((unsigned short)(rb & 0xffffu));
        q1 += wb * bits2f((unsigned short)(rb >> 16));
        r0 += wc * bits2f((unsigned short)(rc & 0xffffu));
        r1 += wc * bits2f((unsigned short)(rc >> 16));
        s0 += wd * bits2f((unsigned short)(rd & 0xffffu));
        s1 += wd * bits2f((unsigned short)(rd >> 16));
    }
    for (; j < end; ++j) {
        const uint2 ev = sorted[j];
        const float w = __uint_as_float(ev.y);
        const unsigned raw = *(const unsigned*)(hb + (size_t)ev.x * NH + lane * 2);
        p0 += w * bits2f((unsigned short)(raw & 0xffffu));
        p1 += w * bits2f((unsigned short)(raw >> 16));
    }
    const float a0 = (p0 + q0) + (r0 + s0);
    const float a1 = (p1 + q1) + (r1 + s1);
    unsigned o = ((unsigned)__bfloat16_as_ushort(f2bf(a1)) << 16) |
                 (unsigned)__bfloat16_as_ushort(f2bf(a0));
    *(unsigned*)((unsigned short*)agg + (size_t)node * NH + lane * 2) = o;
}

// ---------------------------------------------------------------------------
// t = agg @ Wrel^T + h @ Wroot^T + b   (bf16 in, fp32 out)
// Register-resident weights (2 chains x 4 tiles x 4 ksteps = 128 VGPRs).
// Fused column sum/sumsq -> per-block partial[256].
// ---------------------------------------------------------------------------
__global__ __launch_bounds__(256, 2) void gemm_conv_kernel(
    const __hip_bfloat16* __restrict__ agg, const __hip_bfloat16* __restrict__ h,
    const __hip_bfloat16* __restrict__ Wrel, const __hip_bfloat16* __restrict__ Wroot,
    const float* __restrict__ bias, float* __restrict__ out,
    float* __restrict__ partial)
{
    const int waveG = blockIdx.x * 4 + (threadIdx.x >> 6);  // 0..2047
    const int lane = threadIdx.x & 63;
    const int half = waveG & 1;
    const int ar = lane & 15;
    const int q  = lane >> 4;

    bf16x8 brel[4][4], brt[4][4];
    float bv[4];
    #pragma unroll
    for (int t = 0; t < 4; ++t) {
        const int row = half * 64 + t * 16 + ar;
        bv[t] = bias[row];
        #pragma unroll
        for (int k = 0; k < 4; ++k) {
            brel[t][k] = *(const bf16x8*)(Wrel + (size_t)row * NH + k * 32 + q * 8);
            brt[t][k]  = *(const bf16x8*)(Wroot + (size_t)row * NH + k * 32 + q * 8);
        }
    }

    float s1[4] = {}, s2[4] = {};

    for (int strip = waveG >> 1; strip < MTILES; strip += GEMM_BLOCKS * 2) {
        const int m0 = strip << 4;
        floatx4 acc[4] = {};
        #pragma unroll
        for (int k = 0; k < 4; ++k) {
            const bf16x8 a = *(const bf16x8*)(agg + (size_t)(m0 + ar) * NH + k * 32 + q * 8);
            #pragma unroll
            for (int t = 0; t < 4; ++t)
                acc[t] = __builtin_amdgcn_mfma_f32_16x16x32_bf16(a, brel[t][k], acc[t], 0, 0, 0);
        }
        #pragma unroll
        for (int k = 0; k < 4; ++k) {
            const bf16x8 a = *(const bf16x8*)(h + (size_t)(m0 + ar) * NH + k * 32 + q * 8);
            #pragma unroll
            for (int t = 0; t < 4; ++t)
                acc[t] = __builtin_amdgcn_mfma_f32_16x16x32_bf16(a, brt[t][k], acc[t], 0, 0, 0);
        }
        #pragma unroll
        for (int t = 0; t < 4; ++t) {
            const int col = half * 64 + t * 16 + ar;
            #pragma unroll
            for (int r = 0; r < 4; ++r) {
                const float v = acc[t][r] + bv[t];
                out[(size_t)(m0 + q * 4 + r) * NH + col] = v;
                s1[t] += v; s2[t] += v * v;
            }
        }
    }

    __shared__ float sst[256];
    sst[threadIdx.x] = 0.f;
    __syncthreads();
    #pragma unroll
    for (int t = 0; t < 4; ++t) {
        float a = s1[t], b = s2[t];
        a += __shfl_xor(a, 16, 64); a += __shfl_xor(a, 32, 64);
        b += __shfl_xor(b, 16, 64); b += __shfl_xor(b, 32, 64);
        if (q == 0) {
            const int col = half * 64 + t * 16 + ar;
            atomicAdd(&sst[col], a);
            atomicAdd(&sst[128 + col], b);
        }
    }
    __syncthreads();
    partial[blockIdx.x * 256 + threadIdx.x] = sst[threadIdx.x];
}

// ---------------------------------------------------------------------------
// stats[c] = sum over blocks of partial[b][c]
// ---------------------------------------------------------------------------
__global__ __launch_bounds__(256) void reduce_stats_kernel(
    const float* __restrict__ partial, float* __restrict__ stats)
{
    const int tid = threadIdx.x;
    float a = 0.f, b = 0.f, c = 0.f, d = 0.f;
    for (int blk = 0; blk < GEMM_BLOCKS; blk += 4) {
        a += partial[(blk + 0) * 256 + tid];
        b += partial[(blk + 1) * 256 + tid];
        c += partial[(blk + 2) * 256 + tid];
        d += partial[(blk + 3) * 256 + tid];
    }
    stats[tid] = (a + b) + (c + d);
}

// ---------------------------------------------------------------------------
// BN normalize variants
// ---------------------------------------------------------------------------
__global__ __launch_bounds__(256) void bn_relu_bf16_kernel(
    const float* __restrict__ t, const float* __restrict__ stats,
    const float* __restrict__ gamma, const float* __restrict__ beta,
    __hip_bfloat16* __restrict__ out)
{
    const size_t i = (size_t)blockIdx.x * blockDim.x + threadIdx.x;  // exact grid
    const int c = (int)(i & (NH - 1));
    const float inv_n = 1.0f / (float)NNODES;
    const float mu = stats[c] * inv_n;
    const float var = stats[128 + c] * inv_n - mu * mu;
    const float rs = rsqrtf(var + BN_EPS);
    float v = (t[i] - mu) * rs * gamma[c] + beta[c];
    out[i] = f2bf(fmaxf(v, 0.f));
}

__global__ __launch_bounds__(256) void bn_f32_kernel(
    const float* __restrict__ t, const float* __restrict__ stats,
    const float* __restrict__ gamma, const float* __restrict__ beta,
    float* __restrict__ out)
{
    const size_t i = (size_t)blockIdx.x * blockDim.x + threadIdx.x;
    const int c = (int)(i & (NH - 1));
    const float inv_n = 1.0f / (float)NNODES;
    const float mu = stats[c] * inv_n;
    const float var = stats[128 + c] * inv_n - mu * mu;
    const float rs = rsqrtf(var + BN_EPS);
    out[i] = (t[i] - mu) * rs * gamma[c] + beta[c];
}

// ---------------------------------------------------------------------------

extern "C" void kernel_launch(void* const* d_in, const int* in_sizes, int n_in,
                              void* d_out, int out_size, void* d_ws, size_t ws_size,
                              hipStream_t stream)
{
    const float* x    = (const float*)d_in[0];
    const int*   adj  = (const int*)d_in[1];
    const float* ew   = (const float*)d_in[2];
    const float* W_in = (const float*)d_in[3];
    const float* b_in = (const float*)d_in[4];
    const float* W1r  = (const float*)d_in[5];
    const float* b1   = (const float*)d_in[6];
    const float* W1o  = (const float*)d_in[7];
    const float* W2r  = (const float*)d_in[8];
    const float* b2   = (const float*)d_in[9];
    const float* W2o  = (const float*)d_in[10];
    const float* gmm  = (const float*)d_in[11];
    const float* bta  = (const float*)d_in[12];
    float* out = (float*)d_out;          // fp32 output [N, NH]
    float* t   = (float*)d_out;          // pre-BN conv result lives in d_out

    char* ws = (char*)d_ws;
    __hip_bfloat16* h0  = (__hip_bfloat16*)ws; ws += (size_t)NNODES * NH * 2;  // 12.8 MB
    __hip_bfloat16* h1  = (__hip_bfloat16*)ws; ws += (size_t)NNODES * NH * 2;  // 12.8 MB
    __hip_bfloat16* agg = (__hip_bfloat16*)ws; ws += (size_t)NNODES * NH * 2;  // 12.8 MB
    uint2*          sorted  = (uint2*)ws;      ws += (size_t)NBUCKETS * BCAP * 8;  // 7.2 MB
    uint2*          pairbuf = (uint2*)ws;      ws += (size_t)NBUCKETS * BCAP * 8;  // 7.2 MB
    unsigned char*  nodebuf = (unsigned char*)ws; ws += (size_t)NBUCKETS * BCAP;   // 0.9 MB
    int*            rowptr  = (int*)ws;        ws += NNODES * 4;
    int*            rowend  = (int*)ws;        ws += NNODES * 4;
    int*            gcursor = (int*)ws;        ws += ((NBUCKETS + 3) & ~3) * 4;
    __hip_bfloat16* wbf     = (__hip_bfloat16*)ws; ws += 98304 * 2;            // 192 KB
    float*          partial = (float*)ws;      ws += GEMM_BLOCKS * 256 * 4;    // 512 KB
    float*          st      = (float*)ws;      ws += 256 * 4;

    const __hip_bfloat16* Wb_in = wbf;
    const __hip_bfloat16* Wb1r  = wbf + 32768;
    const __hip_bfloat16* Wb1o  = wbf + 49152;
    const __hip_bfloat16* Wb2r  = wbf + 65536;
    const __hip_bfloat16* Wb2o  = wbf + 81920;

    const int node_blocks = (NNODES + 3) / 4;                   // 12500
    const int bn_blocks   = (NNODES * NH) / 256;                // 25000

    // ---- prep: weight conversion (+ cursor init) + two-level bucket CSR ----
    convert_w_kernel<<<98304 / 256, 256, 0, stream>>>(W_in, W1r, W1o, W2r, W2o, wbf, gcursor);
    bucket_scatter_kernel<<<SCAT_BLOCKS, 256, 0, stream>>>(adj, ew, gcursor, pairbuf, nodebuf);
    bucket_sort_kernel<<<NBUCKETS, 256, 0, stream>>>(gcursor, pairbuf, nodebuf,
                                                     sorted, rowptr, rowend);

    // ---- layer 1 ----
    gemm_in_kernel<<<GEMM_BLOCKS, 256, 0, stream>>>(x, Wb_in, b_in, h0);
    gather_kernel<<<node_blocks, 256, 0, stream>>>(sorted, rowptr, rowend, h0, agg);
    gemm_conv_kernel<<<GEMM_BLOCKS, 256, 0, stream>>>(agg, h0, Wb1r, Wb1o, b1, t, partial);
    reduce_stats_kernel<<<1, 256, 0, stream>>>(partial, st);
    bn_relu_bf16_kernel<<<bn_blocks, 256, 0, stream>>>(t, st, gmm, bta, h1);

    // ---- layer 2 ----
    gather_kernel<<<node_blocks, 256, 0, stream>>>(sorted, rowptr, rowend, h1, agg);
    gemm_conv_kernel<<<GEMM_BLOCKS, 256, 0, stream>>>(agg, h1, Wb2r, Wb2o, b2, t, partial);
    reduce_stats_kernel<<<1, 256, 0, stream>>>(partial, st);
    bn_f32_kernel<<<bn_blocks, 256, 0, stream>>>(t, st, gmm, bta, out);
}